// Round 5
// baseline (483.083 us; speedup 1.0000x reference)
//
#include <hip/hip_runtime.h>
#include <hip/hip_bf16.h>

// Problem constants
#define B_SZ 2
#define LSEQ 1024
#define DIN  2048
#define DST  16
#define DTR  64
#define KTOT 96              // DTR + 2*DST
#define NROW (B_SZ * LSEQ)   // 2048 (b,l) rows
#define NCH  64              // number of L-chunks
#define TCH  16              // timesteps per chunk (LSEQ / NCH)
#define KSP  32              // K-splits in k_proj (64 K each)

// bf16 (as ushort) -> float
__device__ __forceinline__ float b2f(unsigned int u) {
    union { unsigned int i; float f; } v;
    v.i = (u & 0xffffu) << 16;
    return v.f;
}

// scalar load: element i of a buffer that is either fp32 or bf16
__device__ __forceinline__ float ldf(const void* p, size_t i, bool f32) {
    return f32 ? ((const float*)p)[i] : b2f(((const unsigned short*)p)[i]);
}

// 4 consecutive elements as float4, dual dtype
__device__ __forceinline__ float4 ld4(const void* p, size_t i, bool f32) {
    if (f32) return *(const float4*)((const float*)p + i);
    const uint2 u = *(const uint2*)((const unsigned short*)p + i);
    float4 v;
    v.x = b2f(u.x); v.y = b2f(u.x >> 16);
    v.z = b2f(u.y); v.w = b2f(u.y >> 16);
    return v;
}

__device__ __forceinline__ float softplus_f(float v) {
    return (v > 20.f) ? v : log1pf(__expf(v));
}

// ---------------------------------------------------------------------------
// Kernel 0: dtype detector. flag=1 -> fp32, flag=0 -> bf16.
// ---------------------------------------------------------------------------
__global__ __launch_bounds__(256) void k_detect(const void* __restrict__ x,
                                                int* __restrict__ flag) {
    __shared__ int cnt;
    if (threadIdx.x == 0) cnt = 0;
    __syncthreads();
    const unsigned short* u = (const unsigned short*)x;
    int my = 0;
    for (int i = threadIdx.x; i < 4096; i += 256) {
        unsigned short v = u[2 * i];
        float af = fabsf(b2f(v));
        if (v == 0 || (af >= 6.0e-8f && af <= 1.7e7f)) my++;
    }
    atomicAdd(&cnt, my);
    __syncthreads();
    if (threadIdx.x == 0) *flag = (cnt < 2048) ? 1 : 0;
}

// ---------------------------------------------------------------------------
// Kernel 1: input projection, tiled split-K GEMM.
// C[2048][96] = x[2048][2048] . Wx^T. Tile 64 rows x 96 cols x 64 K.
// ---------------------------------------------------------------------------
__global__ __launch_bounds__(256, 4) void k_proj(
    const void* __restrict__ x,      // [NROW][DIN]
    const void* __restrict__ Wx,     // [96][DIN]
    const int*  __restrict__ flag,
    float* __restrict__ part)        // [KSP][NROW][96]
{
    const bool f32 = (*flag != 0);
    __shared__ float lx[32][68];     // [k][row], padded
    __shared__ float lw[32][100];    // [k][col], padded
    const int tid = threadIdx.x;
    const int bx = blockIdx.x;       // row group (64 rows)
    const int by = blockIdx.y;       // K-split (64 K)
    const int rt = tid >> 4, ct = tid & 15;
    const int r0 = rt * 4, c0 = ct * 6;

    float acc[4][6];
    #pragma unroll
    for (int i = 0; i < 4; i++)
        #pragma unroll
        for (int k = 0; k < 6; k++) acc[i][k] = 0.f;

    for (int half = 0; half < 2; half++) {
        const int k0 = by * 64 + half * 32;
        #pragma unroll
        for (int it = 0; it < 2; it++) {
            const int idx = tid + it * 256;
            const int r = idx >> 3, q = idx & 7;
            float4 v = ld4(x, (size_t)(bx * 64 + r) * DIN + k0 + q * 4, f32);
            lx[q * 4 + 0][r] = v.x; lx[q * 4 + 1][r] = v.y;
            lx[q * 4 + 2][r] = v.z; lx[q * 4 + 3][r] = v.w;
        }
        #pragma unroll
        for (int it = 0; it < 3; it++) {
            const int idx = tid + it * 256;
            const int c = idx >> 3, q = idx & 7;
            float4 v = ld4(Wx, (size_t)c * DIN + k0 + q * 4, f32);
            lw[q * 4 + 0][c] = v.x; lw[q * 4 + 1][c] = v.y;
            lw[q * 4 + 2][c] = v.z; lw[q * 4 + 3][c] = v.w;
        }
        __syncthreads();

        #pragma unroll 4
        for (int j = 0; j < 32; j++) {
            const float4 xa = *(const float4*)&lx[j][r0];
            const float2 w0 = *(const float2*)&lw[j][c0];
            const float2 w1 = *(const float2*)&lw[j][c0 + 2];
            const float2 w2 = *(const float2*)&lw[j][c0 + 4];
            const float xr[4] = {xa.x, xa.y, xa.z, xa.w};
            const float wc[6] = {w0.x, w0.y, w1.x, w1.y, w2.x, w2.y};
            #pragma unroll
            for (int i = 0; i < 4; i++)
                #pragma unroll
                for (int k = 0; k < 6; k++)
                    acc[i][k] += xr[i] * wc[k];
        }
        __syncthreads();
    }

    float* p = part + ((size_t)by * NROW + bx * 64 + r0) * KTOT + c0;
    #pragma unroll
    for (int i = 0; i < 4; i++) {
        float* row = p + (size_t)i * KTOT;
        *(float2*)(row)     = make_float2(acc[i][0], acc[i][1]);
        *(float2*)(row + 2) = make_float2(acc[i][2], acc[i][3]);
        *(float2*)(row + 4) = make_float2(acc[i][4], acc[i][5]);
    }
}

// ---------------------------------------------------------------------------
// Kernel 2: combine K-split partials -> drw / Bin / Cin.
// ---------------------------------------------------------------------------
__global__ __launch_bounds__(256, 4) void k_comb(
    const float* __restrict__ part,
    float* __restrict__ drw, float* __restrict__ Bin, float* __restrict__ Cin)
{
    const int idx = blockIdx.x * 256 + threadIdx.x;   // < NROW*96
    float s = 0.f;
    #pragma unroll 8
    for (int ks = 0; ks < KSP; ks++)
        s += part[(size_t)ks * NROW * KTOT + idx];
    const int r = idx / KTOT, c = idx % KTOT;
    if (c < DTR)            drw[r * DTR + c] = s;
    else if (c < DTR + DST) Bin[r * DST + (c - DTR)] = s;
    else                    Cin[r * DST + (c - DTR - DST)] = s;
}

// ---------------------------------------------------------------------------
// Kernel 3 (scan phase 1, fused dt, LDS-staged). Round-4 post-mortem: keeping
// dtv[16] in regs alongside P/H/A spilled (~80-90 live regs, allocator chose
// 64) -> 528 MB of scratch HBM traffic, 156 us. Fix: t-loop touches ONLY LDS
// (x_lds, dt_lds, Bs) + 48 reg accumulators. Also removes the old in-loop
// scalar global-load latency (round-1 scans were latency-bound at ~55 us).
//   LDS: x 16K + dt 16K + drw 4K + Bs 1K = 37.9 KB -> 4 blocks/CU.
//   dt_lds[t][tid]: each thread writes/reads only its own column -> no
//   barrier needed between dt compute and scan.
// ---------------------------------------------------------------------------
__global__ __launch_bounds__(256, 4) void k_scan1(
    const void* __restrict__ x,
    const float* __restrict__ drw,   // [NROW][DTR]
    const float* __restrict__ Bin,
    const void* __restrict__ Wdt,    // [DIN][DTR]
    const void* __restrict__ bdt,    // [DIN]
    const void* __restrict__ Alog,
    const int*  __restrict__ flag,
    float* __restrict__ Pb,          // [B][NCH][DST][DIN]
    float* __restrict__ Hb)
{
    const bool f32 = (*flag != 0);
    __shared__ float x_lds[TCH][256];
    __shared__ float dt_lds[TCH][256];
    __shared__ float drw_lds[TCH][DTR];
    __shared__ float Bs[TCH * DST];  // 256 floats
    const int tid = threadIdx.x;
    const int d = blockIdx.x * 256 + tid;
    const int c = blockIdx.y;
    const int b = blockIdx.z;
    const int row0 = b * LSEQ + c * TCH;

    // ---- stage x chunk [16 t][256 d], coalesced float4 ----
    #pragma unroll
    for (int it = 0; it < 4; it++) {
        const int f4 = tid + it * 256;           // < 1024
        const int t  = f4 >> 6, q4 = f4 & 63;
        float4 v = ld4(x, (size_t)(row0 + t) * DIN + blockIdx.x * 256 + q4 * 4, f32);
        *(float4*)&x_lds[t][q4 * 4] = v;
    }
    // ---- stage drw chunk [16 r][64 k], coalesced ----
    #pragma unroll
    for (int it = 0; it < 4; it++) {
        const int f = tid + it * 256;            // < 1024
        const int r = f >> 6, k = f & 63;
        drw_lds[r][k] = drw[(size_t)(row0 + r) * DTR + k];
    }
    Bs[tid] = Bin[(size_t)row0 * DST + tid];     // TCH*DST == 256

    float A[DST];
    #pragma unroll
    for (int sq = 0; sq < DST / 4; sq++) {
        float4 av = ld4(Alog, (size_t)d * DST + sq * 4, f32);
        A[sq * 4 + 0] = -__expf(av.x); A[sq * 4 + 1] = -__expf(av.y);
        A[sq * 4 + 2] = -__expf(av.z); A[sq * 4 + 3] = -__expf(av.w);
    }
    __syncthreads();

    // ---- fused dt: dtv[r] = softplus(bdt[d] + drw[row0+r].Wdt[d]) -> LDS ----
    {
        float dtv[TCH];
        const float bd = ldf(bdt, (size_t)d, f32);
        #pragma unroll
        for (int r = 0; r < TCH; r++) dtv[r] = bd;
        #pragma unroll 4
        for (int kq = 0; kq < DTR / 4; kq++) {
            const float4 w = ld4(Wdt, (size_t)d * DTR + kq * 4, f32);
            #pragma unroll
            for (int r = 0; r < TCH; r++) {
                const float4 a = *(const float4*)&drw_lds[r][kq * 4];
                dtv[r] += a.x * w.x; dtv[r] += a.y * w.y;
                dtv[r] += a.z * w.z; dtv[r] += a.w * w.w;
            }
        }
        #pragma unroll
        for (int r = 0; r < TCH; r++) dt_lds[r][tid] = softplus_f(dtv[r]);
    }
    // no barrier: each thread reads back only its own dt_lds column

    float P[DST], H[DST];
    #pragma unroll
    for (int s = 0; s < DST; s++) { P[s] = 1.f; H[s] = 0.f; }

    #pragma unroll
    for (int t = 0; t < TCH; t++) {
        const float dtv_t = dt_lds[t][tid];
        const float xv    = x_lds[t][tid];
        const float u     = dtv_t * xv;
        const float* bs = Bs + t * DST;
        #pragma unroll
        for (int s = 0; s < DST; s++) {
            const float e = __expf(dtv_t * A[s]);
            P[s] *= e;
            H[s] = e * H[s] + u * bs[s];
        }
    }

    const size_t base = (size_t)(b * NCH + c) * DST * DIN + d;
    #pragma unroll
    for (int s = 0; s < DST; s++) {
        Pb[base + (size_t)s * DIN] = P[s];
        Hb[base + (size_t)s * DIN] = H[s];
    }
}

// ---------------------------------------------------------------------------
// Kernel 4 (scan phase 2): cross-chunk exclusive scan per (b,s,d).
// ---------------------------------------------------------------------------
__global__ __launch_bounds__(256, 4) void k_scan2(
    const float* __restrict__ Pb,
    const float* __restrict__ Hb,
    float* __restrict__ hin)
{
    const int idx = blockIdx.x * 256 + threadIdx.x;
    const int b   = idx / (DST * DIN);
    const int rem = idx % (DST * DIN);
    float h = 0.f;
    #pragma unroll 4
    for (int c = 0; c < NCH; c++) {
        const size_t o = (size_t)(b * NCH + c) * DST * DIN + rem;
        const float p = Pb[o], hb = Hb[o];
        hin[o] = h;
        h = hb + p * h;
    }
}

// ---------------------------------------------------------------------------
// Kernel 5 (scan phase 3, fused dt, LDS-staged): seeded with hin, emit y.
// dt computed identically to k_scan1 -> bitwise-consistent across phases.
// LDS: x 16K + dt 16K + drw 4K + Bs 1K + Cs 1K = 38.9 KB -> 4 blocks/CU.
// ---------------------------------------------------------------------------
__global__ __launch_bounds__(256, 4) void k_scan3(
    const void* __restrict__ x,
    const float* __restrict__ drw,
    const float* __restrict__ Bin,
    const float* __restrict__ Cin,
    const void* __restrict__ Wdt,
    const void* __restrict__ bdt,
    const void* __restrict__ Alog,
    const void* __restrict__ Dv,
    const float* __restrict__ hin,
    const int*  __restrict__ flag,
    void* __restrict__ y)
{
    const bool f32 = (*flag != 0);
    __shared__ float x_lds[TCH][256];
    __shared__ float dt_lds[TCH][256];
    __shared__ float drw_lds[TCH][DTR];
    __shared__ float Bs[TCH * DST];
    __shared__ float Cs[TCH * DST];
    const int tid = threadIdx.x;
    const int d = blockIdx.x * 256 + tid;
    const int c = blockIdx.y;
    const int b = blockIdx.z;
    const int row0 = b * LSEQ + c * TCH;

    #pragma unroll
    for (int it = 0; it < 4; it++) {
        const int f4 = tid + it * 256;
        const int t  = f4 >> 6, q4 = f4 & 63;
        float4 v = ld4(x, (size_t)(row0 + t) * DIN + blockIdx.x * 256 + q4 * 4, f32);
        *(float4*)&x_lds[t][q4 * 4] = v;
    }
    #pragma unroll
    for (int it = 0; it < 4; it++) {
        const int f = tid + it * 256;
        const int r = f >> 6, k = f & 63;
        drw_lds[r][k] = drw[(size_t)(row0 + r) * DTR + k];
    }
    Bs[tid] = Bin[(size_t)row0 * DST + tid];
    Cs[tid] = Cin[(size_t)row0 * DST + tid];

    float A[DST];
    #pragma unroll
    for (int sq = 0; sq < DST / 4; sq++) {
        float4 av = ld4(Alog, (size_t)d * DST + sq * 4, f32);
        A[sq * 4 + 0] = -__expf(av.x); A[sq * 4 + 1] = -__expf(av.y);
        A[sq * 4 + 2] = -__expf(av.z); A[sq * 4 + 3] = -__expf(av.w);
    }
    const float Dd = ldf(Dv, (size_t)d, f32);
    __syncthreads();

    {
        float dtv[TCH];
        const float bd = ldf(bdt, (size_t)d, f32);
        #pragma unroll
        for (int r = 0; r < TCH; r++) dtv[r] = bd;
        #pragma unroll 4
        for (int kq = 0; kq < DTR / 4; kq++) {
            const float4 w = ld4(Wdt, (size_t)d * DTR + kq * 4, f32);
            #pragma unroll
            for (int r = 0; r < TCH; r++) {
                const float4 a = *(const float4*)&drw_lds[r][kq * 4];
                dtv[r] += a.x * w.x; dtv[r] += a.y * w.y;
                dtv[r] += a.z * w.z; dtv[r] += a.w * w.w;
            }
        }
        #pragma unroll
        for (int r = 0; r < TCH; r++) dt_lds[r][tid] = softplus_f(dtv[r]);
    }

    float h[DST];
    const size_t base = (size_t)(b * NCH + c) * DST * DIN + d;
    #pragma unroll
    for (int s = 0; s < DST; s++) h[s] = hin[base + (size_t)s * DIN];

    #pragma unroll
    for (int t = 0; t < TCH; t++) {
        const float dtv_t = dt_lds[t][tid];
        const float xv    = x_lds[t][tid];
        const float u     = dtv_t * xv;
        const float* bs = Bs + t * DST;
        const float* cs = Cs + t * DST;
        float yv = Dd * xv;
        #pragma unroll
        for (int s = 0; s < DST; s++) {
            const float e = __expf(dtv_t * A[s]);
            h[s] = e * h[s] + u * bs[s];
            yv += h[s] * cs[s];
        }
        const size_t off = (size_t)(row0 + t) * DIN + d;
        if (f32) ((float*)y)[off] = yv;
        else     ((__hip_bfloat16*)y)[off] = __float2bfloat16(yv);
    }
}

// ---------------------------------------------------------------------------
extern "C" void kernel_launch(void* const* d_in, const int* in_sizes, int n_in,
                              void* d_out, int out_size, void* d_ws, size_t ws_size,
                              hipStream_t stream) {
    const void* x    = d_in[0];
    const void* Wx   = d_in[1];
    const void* Wdt  = d_in[2];
    const void* bdt  = d_in[3];
    const void* Alog = d_in[4];
    const void* Dv   = d_in[5];

    // ---- workspace layout, NO aliasing (~77 MB; ws is >=268 MB) ----
    int*   flag  = (int*)d_ws;
    float* basep = (float*)d_ws + 16;
    float* drw   = basep;                                  // NROW*DTR   = 131072
    float* Bin   = drw + (size_t)NROW * DTR;               // NROW*DST   = 32768
    float* Cin   = Bin + (size_t)NROW * DST;               // NROW*DST   = 32768
    float* part  = Cin + (size_t)NROW * DST;               // KSP*NROW*96 = 6291456
    float* Pb    = part + (size_t)KSP * NROW * KTOT;       // B*NCH*DST*DIN = 4194304
    float* Hb    = Pb + (size_t)B_SZ * NCH * DST * DIN;    // 4194304
    float* hin   = Hb + (size_t)B_SZ * NCH * DST * DIN;    // 4194304

    k_detect<<<1, 256, 0, stream>>>(x, flag);

    k_proj<<<dim3(NROW / 64, KSP), 256, 0, stream>>>(x, Wx, flag, part);

    k_comb<<<(NROW * KTOT) / 256, 256, 0, stream>>>(part, drw, Bin, Cin);

    dim3 g1(DIN / 256, NCH, B_SZ);
    k_scan1<<<g1, 256, 0, stream>>>(x, drw, Bin, Wdt, bdt, Alog, flag, Pb, Hb);

    k_scan2<<<(B_SZ * DST * DIN) / 256, 256, 0, stream>>>(Pb, Hb, hin);

    k_scan3<<<g1, 256, 0, stream>>>(x, drw, Bin, Cin, Wdt, bdt, Alog, Dv, hin, flag, d_out);
}

// Round 6
// 208.067 us; speedup vs baseline: 2.3218x; 2.3218x over previous
//
#include <hip/hip_runtime.h>
#include <hip/hip_bf16.h>

// Problem constants
#define B_SZ 2
#define LSEQ 1024
#define DIN  2048
#define DST  16
#define DTR  64
#define KTOT 96              // DTR + 2*DST
#define NROW (B_SZ * LSEQ)   // 2048 (b,l) rows
#define NCH  64              // number of L-chunks
#define TCH  16              // timesteps per chunk (LSEQ / NCH)
#define KSP  32              // K-splits in k_proj (64 K each)

// bf16 (as ushort) -> float
__device__ __forceinline__ float b2f(unsigned int u) {
    union { unsigned int i; float f; } v;
    v.i = (u & 0xffffu) << 16;
    return v.f;
}

// scalar load: element i of a buffer that is either fp32 or bf16
__device__ __forceinline__ float ldf(const void* p, size_t i, bool f32) {
    return f32 ? ((const float*)p)[i] : b2f(((const unsigned short*)p)[i]);
}

// 4 consecutive elements as float4, dual dtype
__device__ __forceinline__ float4 ld4(const void* p, size_t i, bool f32) {
    if (f32) return *(const float4*)((const float*)p + i);
    const uint2 u = *(const uint2*)((const unsigned short*)p + i);
    float4 v;
    v.x = b2f(u.x); v.y = b2f(u.x >> 16);
    v.z = b2f(u.y); v.w = b2f(u.y >> 16);
    return v;
}

__device__ __forceinline__ float softplus_f(float v) {
    return (v > 20.f) ? v : log1pf(__expf(v));
}

// ---------------------------------------------------------------------------
// Kernel 0: dtype detector. flag=1 -> fp32, flag=0 -> bf16.
// ---------------------------------------------------------------------------
__global__ __launch_bounds__(256) void k_detect(const void* __restrict__ x,
                                                int* __restrict__ flag) {
    __shared__ int cnt;
    if (threadIdx.x == 0) cnt = 0;
    __syncthreads();
    const unsigned short* u = (const unsigned short*)x;
    int my = 0;
    for (int i = threadIdx.x; i < 4096; i += 256) {
        unsigned short v = u[2 * i];
        float af = fabsf(b2f(v));
        if (v == 0 || (af >= 6.0e-8f && af <= 1.7e7f)) my++;
    }
    atomicAdd(&cnt, my);
    __syncthreads();
    if (threadIdx.x == 0) *flag = (cnt < 2048) ? 1 : 0;
}

// ---------------------------------------------------------------------------
// Kernel 1: input projection, tiled split-K GEMM.
// C[2048][96] = x[2048][2048] . Wx^T. Tile 64 rows x 96 cols x 64 K.
// ---------------------------------------------------------------------------
__global__ __launch_bounds__(256, 4) void k_proj(
    const void* __restrict__ x,      // [NROW][DIN]
    const void* __restrict__ Wx,     // [96][DIN]
    const int*  __restrict__ flag,
    float* __restrict__ part)        // [KSP][NROW][96]
{
    const bool f32 = (*flag != 0);
    __shared__ float lx[32][68];     // [k][row], padded
    __shared__ float lw[32][100];    // [k][col], padded
    const int tid = threadIdx.x;
    const int bx = blockIdx.x;       // row group (64 rows)
    const int by = blockIdx.y;       // K-split (64 K)
    const int rt = tid >> 4, ct = tid & 15;
    const int r0 = rt * 4, c0 = ct * 6;

    float acc[4][6];
    #pragma unroll
    for (int i = 0; i < 4; i++)
        #pragma unroll
        for (int k = 0; k < 6; k++) acc[i][k] = 0.f;

    for (int half = 0; half < 2; half++) {
        const int k0 = by * 64 + half * 32;
        #pragma unroll
        for (int it = 0; it < 2; it++) {
            const int idx = tid + it * 256;
            const int r = idx >> 3, q = idx & 7;
            float4 v = ld4(x, (size_t)(bx * 64 + r) * DIN + k0 + q * 4, f32);
            lx[q * 4 + 0][r] = v.x; lx[q * 4 + 1][r] = v.y;
            lx[q * 4 + 2][r] = v.z; lx[q * 4 + 3][r] = v.w;
        }
        #pragma unroll
        for (int it = 0; it < 3; it++) {
            const int idx = tid + it * 256;
            const int c = idx >> 3, q = idx & 7;
            float4 v = ld4(Wx, (size_t)c * DIN + k0 + q * 4, f32);
            lw[q * 4 + 0][c] = v.x; lw[q * 4 + 1][c] = v.y;
            lw[q * 4 + 2][c] = v.z; lw[q * 4 + 3][c] = v.w;
        }
        __syncthreads();

        #pragma unroll 4
        for (int j = 0; j < 32; j++) {
            const float4 xa = *(const float4*)&lx[j][r0];
            const float2 w0 = *(const float2*)&lw[j][c0];
            const float2 w1 = *(const float2*)&lw[j][c0 + 2];
            const float2 w2 = *(const float2*)&lw[j][c0 + 4];
            const float xr[4] = {xa.x, xa.y, xa.z, xa.w};
            const float wc[6] = {w0.x, w0.y, w1.x, w1.y, w2.x, w2.y};
            #pragma unroll
            for (int i = 0; i < 4; i++)
                #pragma unroll
                for (int k = 0; k < 6; k++)
                    acc[i][k] += xr[i] * wc[k];
        }
        __syncthreads();
    }

    float* p = part + ((size_t)by * NROW + bx * 64 + r0) * KTOT + c0;
    #pragma unroll
    for (int i = 0; i < 4; i++) {
        float* row = p + (size_t)i * KTOT;
        *(float2*)(row)     = make_float2(acc[i][0], acc[i][1]);
        *(float2*)(row + 2) = make_float2(acc[i][2], acc[i][3]);
        *(float2*)(row + 4) = make_float2(acc[i][4], acc[i][5]);
    }
}

// ---------------------------------------------------------------------------
// Kernel 2: combine K-split partials -> drw / Bin / Cin.
// ---------------------------------------------------------------------------
__global__ __launch_bounds__(256, 4) void k_comb(
    const float* __restrict__ part,
    float* __restrict__ drw, float* __restrict__ Bin, float* __restrict__ Cin)
{
    const int idx = blockIdx.x * 256 + threadIdx.x;   // < NROW*96
    float s = 0.f;
    #pragma unroll 8
    for (int ks = 0; ks < KSP; ks++)
        s += part[(size_t)ks * NROW * KTOT + idx];
    const int r = idx / KTOT, c = idx % KTOT;
    if (c < DTR)            drw[r * DTR + c] = s;
    else if (c < DTR + DST) Bin[r * DST + (c - DTR)] = s;
    else                    Cin[r * DST + (c - DTR - DST)] = s;
}

// ---------------------------------------------------------------------------
// Kernel 3 (scan phase 1, fused dt, LDS-staged, ROLLED t-loop).
// Round-5 post-mortem: FULL unroll of the 16-t loop hoisted all LDS loads +
// store addresses -> ~90 live regs vs allocator's 64 -> ~700 MB scratch
// round-trips (15x write amplification). Fix: #pragma unroll 1 on the t-loop
// (runtime t indexes only LDS - legal), s-chains give 16-way ILP inside each
// iteration. Live state = A[16]+P[16]+H[16]+temps ~ 58 regs.
// __launch_bounds__(256,2): VGPR cap 256 so the allocator has headroom; LDS
// (37.9 KB) caps residency at 4 blocks/CU anyway.
// ---------------------------------------------------------------------------
__global__ __launch_bounds__(256, 2) void k_scan1(
    const void* __restrict__ x,
    const float* __restrict__ drw,   // [NROW][DTR]
    const float* __restrict__ Bin,
    const void* __restrict__ Wdt,    // [DIN][DTR]
    const void* __restrict__ bdt,    // [DIN]
    const void* __restrict__ Alog,
    const int*  __restrict__ flag,
    float* __restrict__ Pb,          // [B][NCH][DST][DIN]
    float* __restrict__ Hb)
{
    const bool f32 = (*flag != 0);
    __shared__ float x_lds[TCH][256];
    __shared__ float dt_lds[TCH][256];
    __shared__ float drw_lds[TCH][DTR];
    __shared__ float Bs[TCH * DST];  // 256 floats
    const int tid = threadIdx.x;
    const int d = blockIdx.x * 256 + tid;
    const int c = blockIdx.y;
    const int b = blockIdx.z;
    const int row0 = b * LSEQ + c * TCH;

    // ---- stage x chunk [16 t][256 d], coalesced float4 ----
    #pragma unroll
    for (int it = 0; it < 4; it++) {
        const int f4 = tid + it * 256;           // < 1024
        const int t  = f4 >> 6, q4 = f4 & 63;
        float4 v = ld4(x, (size_t)(row0 + t) * DIN + blockIdx.x * 256 + q4 * 4, f32);
        *(float4*)&x_lds[t][q4 * 4] = v;
    }
    // ---- stage drw chunk [16 r][64 k], coalesced ----
    #pragma unroll
    for (int it = 0; it < 4; it++) {
        const int f = tid + it * 256;            // < 1024
        const int r = f >> 6, k = f & 63;
        drw_lds[r][k] = drw[(size_t)(row0 + r) * DTR + k];
    }
    Bs[tid] = Bin[(size_t)row0 * DST + tid];     // TCH*DST == 256

    float A[DST];
    #pragma unroll
    for (int sq = 0; sq < DST / 4; sq++) {
        float4 av = ld4(Alog, (size_t)d * DST + sq * 4, f32);
        A[sq * 4 + 0] = -__expf(av.x); A[sq * 4 + 1] = -__expf(av.y);
        A[sq * 4 + 2] = -__expf(av.z); A[sq * 4 + 3] = -__expf(av.w);
    }
    __syncthreads();

    // ---- fused dt: dtv[r] = softplus(bdt[d] + drw[row0+r].Wdt[d]) -> LDS ----
    {
        float dtv[TCH];
        const float bd = ldf(bdt, (size_t)d, f32);
        #pragma unroll
        for (int r = 0; r < TCH; r++) dtv[r] = bd;
        #pragma unroll 4
        for (int kq = 0; kq < DTR / 4; kq++) {
            const float4 w = ld4(Wdt, (size_t)d * DTR + kq * 4, f32);
            #pragma unroll
            for (int r = 0; r < TCH; r++) {
                const float4 a = *(const float4*)&drw_lds[r][kq * 4];
                dtv[r] += a.x * w.x; dtv[r] += a.y * w.y;
                dtv[r] += a.z * w.z; dtv[r] += a.w * w.w;
            }
        }
        #pragma unroll
        for (int r = 0; r < TCH; r++) dt_lds[r][tid] = softplus_f(dtv[r]);
    }
    // no barrier: each thread reads back only its own dt_lds column

    float P[DST], H[DST];
    #pragma unroll
    for (int s = 0; s < DST; s++) { P[s] = 1.f; H[s] = 0.f; }

    #pragma unroll 1
    for (int t = 0; t < TCH; t++) {
        const float dtv_t = dt_lds[t][tid];
        const float xv    = x_lds[t][tid];
        const float u     = dtv_t * xv;
        const float* bs = Bs + t * DST;
        #pragma unroll
        for (int s = 0; s < DST; s++) {
            const float e = __expf(dtv_t * A[s]);
            P[s] *= e;
            H[s] = e * H[s] + u * bs[s];
        }
    }

    const size_t base = (size_t)(b * NCH + c) * DST * DIN + d;
    #pragma unroll
    for (int s = 0; s < DST; s++) {
        Pb[base + (size_t)s * DIN] = P[s];
        Hb[base + (size_t)s * DIN] = H[s];
    }
}

// ---------------------------------------------------------------------------
// Kernel 4 (scan phase 2): cross-chunk exclusive scan per (b,s,d).
// ---------------------------------------------------------------------------
__global__ __launch_bounds__(256, 4) void k_scan2(
    const float* __restrict__ Pb,
    const float* __restrict__ Hb,
    float* __restrict__ hin)
{
    const int idx = blockIdx.x * 256 + threadIdx.x;
    const int b   = idx / (DST * DIN);
    const int rem = idx % (DST * DIN);
    float h = 0.f;
    #pragma unroll 4
    for (int c = 0; c < NCH; c++) {
        const size_t o = (size_t)(b * NCH + c) * DST * DIN + rem;
        const float p = Pb[o], hb = Hb[o];
        hin[o] = h;
        h = hb + p * h;
    }
}

// ---------------------------------------------------------------------------
// Kernel 5 (scan phase 3, fused dt, LDS-staged, ROLLED t-loop): seeded with
// hin, emit y. Same spill fix as k_scan1. dt computed identically to k_scan1
// -> bitwise-consistent across phases.
// ---------------------------------------------------------------------------
__global__ __launch_bounds__(256, 2) void k_scan3(
    const void* __restrict__ x,
    const float* __restrict__ drw,
    const float* __restrict__ Bin,
    const float* __restrict__ Cin,
    const void* __restrict__ Wdt,
    const void* __restrict__ bdt,
    const void* __restrict__ Alog,
    const void* __restrict__ Dv,
    const float* __restrict__ hin,
    const int*  __restrict__ flag,
    void* __restrict__ y)
{
    const bool f32 = (*flag != 0);
    __shared__ float x_lds[TCH][256];
    __shared__ float dt_lds[TCH][256];
    __shared__ float drw_lds[TCH][DTR];
    __shared__ float Bs[TCH * DST];
    __shared__ float Cs[TCH * DST];
    const int tid = threadIdx.x;
    const int d = blockIdx.x * 256 + tid;
    const int c = blockIdx.y;
    const int b = blockIdx.z;
    const int row0 = b * LSEQ + c * TCH;

    #pragma unroll
    for (int it = 0; it < 4; it++) {
        const int f4 = tid + it * 256;
        const int t  = f4 >> 6, q4 = f4 & 63;
        float4 v = ld4(x, (size_t)(row0 + t) * DIN + blockIdx.x * 256 + q4 * 4, f32);
        *(float4*)&x_lds[t][q4 * 4] = v;
    }
    #pragma unroll
    for (int it = 0; it < 4; it++) {
        const int f = tid + it * 256;
        const int r = f >> 6, k = f & 63;
        drw_lds[r][k] = drw[(size_t)(row0 + r) * DTR + k];
    }
    Bs[tid] = Bin[(size_t)row0 * DST + tid];
    Cs[tid] = Cin[(size_t)row0 * DST + tid];

    float A[DST];
    #pragma unroll
    for (int sq = 0; sq < DST / 4; sq++) {
        float4 av = ld4(Alog, (size_t)d * DST + sq * 4, f32);
        A[sq * 4 + 0] = -__expf(av.x); A[sq * 4 + 1] = -__expf(av.y);
        A[sq * 4 + 2] = -__expf(av.z); A[sq * 4 + 3] = -__expf(av.w);
    }
    const float Dd = ldf(Dv, (size_t)d, f32);
    __syncthreads();

    {
        float dtv[TCH];
        const float bd = ldf(bdt, (size_t)d, f32);
        #pragma unroll
        for (int r = 0; r < TCH; r++) dtv[r] = bd;
        #pragma unroll 4
        for (int kq = 0; kq < DTR / 4; kq++) {
            const float4 w = ld4(Wdt, (size_t)d * DTR + kq * 4, f32);
            #pragma unroll
            for (int r = 0; r < TCH; r++) {
                const float4 a = *(const float4*)&drw_lds[r][kq * 4];
                dtv[r] += a.x * w.x; dtv[r] += a.y * w.y;
                dtv[r] += a.z * w.z; dtv[r] += a.w * w.w;
            }
        }
        #pragma unroll
        for (int r = 0; r < TCH; r++) dt_lds[r][tid] = softplus_f(dtv[r]);
    }

    float h[DST];
    const size_t base = (size_t)(b * NCH + c) * DST * DIN + d;
    #pragma unroll
    for (int s = 0; s < DST; s++) h[s] = hin[base + (size_t)s * DIN];

    #pragma unroll 1
    for (int t = 0; t < TCH; t++) {
        const float dtv_t = dt_lds[t][tid];
        const float xv    = x_lds[t][tid];
        const float u     = dtv_t * xv;
        const float* bs = Bs + t * DST;
        const float* cs = Cs + t * DST;
        float yv = Dd * xv;
        #pragma unroll
        for (int s = 0; s < DST; s++) {
            const float e = __expf(dtv_t * A[s]);
            h[s] = e * h[s] + u * bs[s];
            yv += h[s] * cs[s];
        }
        const size_t off = (size_t)(row0 + t) * DIN + d;
        if (f32) ((float*)y)[off] = yv;
        else     ((__hip_bfloat16*)y)[off] = __float2bfloat16(yv);
    }
}

// ---------------------------------------------------------------------------
extern "C" void kernel_launch(void* const* d_in, const int* in_sizes, int n_in,
                              void* d_out, int out_size, void* d_ws, size_t ws_size,
                              hipStream_t stream) {
    const void* x    = d_in[0];
    const void* Wx   = d_in[1];
    const void* Wdt  = d_in[2];
    const void* bdt  = d_in[3];
    const void* Alog = d_in[4];
    const void* Dv   = d_in[5];

    // ---- workspace layout, NO aliasing (~77 MB; ws is >=268 MB) ----
    int*   flag  = (int*)d_ws;
    float* basep = (float*)d_ws + 16;
    float* drw   = basep;                                  // NROW*DTR   = 131072
    float* Bin   = drw + (size_t)NROW * DTR;               // NROW*DST   = 32768
    float* Cin   = Bin + (size_t)NROW * DST;               // NROW*DST   = 32768
    float* part  = Cin + (size_t)NROW * DST;               // KSP*NROW*96 = 6291456
    float* Pb    = part + (size_t)KSP * NROW * KTOT;       // B*NCH*DST*DIN = 4194304
    float* Hb    = Pb + (size_t)B_SZ * NCH * DST * DIN;    // 4194304
    float* hin   = Hb + (size_t)B_SZ * NCH * DST * DIN;    // 4194304

    k_detect<<<1, 256, 0, stream>>>(x, flag);

    k_proj<<<dim3(NROW / 64, KSP), 256, 0, stream>>>(x, Wx, flag, part);

    k_comb<<<(NROW * KTOT) / 256, 256, 0, stream>>>(part, drw, Bin, Cin);

    dim3 g1(DIN / 256, NCH, B_SZ);
    k_scan1<<<g1, 256, 0, stream>>>(x, drw, Bin, Wdt, bdt, Alog, flag, Pb, Hb);

    k_scan2<<<(B_SZ * DST * DIN) / 256, 256, 0, stream>>>(Pb, Hb, hin);

    k_scan3<<<g1, 256, 0, stream>>>(x, drw, Bin, Cin, Wdt, bdt, Alog, Dv, hin, flag, d_out);
}